// Round 3
// baseline (2240.235 us; speedup 1.0000x reference)
//
#include <hip/hip_runtime.h>
#include <hip/hip_bf16.h>
#include <cstdint>

using bf16 = __hip_bfloat16;

#define N_NODES   50000
#define FEAT      128
#define OUTF      256
#define INV_SQRT3 0.57735026918962576f

#define ACC_FLOATS (N_NODES * OUTF)              // 12,800,000
#define NW         (64 + 64*64 + 64*128)         // 12,352 weights

// All scratch in device globals; d_ws untouched.
__device__ float g_acc[ACC_FLOATS];              // 51.2 MB fp32 accumulator
__device__ float g_wf[NW];                       // fp32 weights
__device__ float g_lut[65536 * 128];             // 32 MB mix LUT (per bf16 pattern)
// flags: [0] snd is int64-words, [1] rcv is int64-words,
//        [2] nf is bf16, [3] ea is bf16, [4] w0 bf16, [5] w1 bf16, [6] w2 bf16
__device__ int g_flags[8];

__device__ __forceinline__ float b2f(uint32_t b) {
    union { uint32_t u; float f; } v; v.u = b << 16; return v.f;
}
__device__ __forceinline__ uint32_t f2b_bits(float f) {
    // round-to-nearest bf16 bits
    union { float f; uint32_t u; } v; v.f = f;
    uint32_t u = v.u;
    uint32_t lsb = (u >> 16) & 1u;
    u += 0x7fffu + lsb;
    return u >> 16;
}
__device__ __forceinline__ float swishf(float x) {
    return x / (1.0f + __expf(-x));
}
// integer-domain sanitize (fast-math-proof): |x| >= 2^14, inf, NaN -> 0
__device__ __forceinline__ float sane(float x) {
    union { float f; uint32_t u; } v; v.f = x;
    uint32_t e = (v.u >> 23) & 0xffu;
    return (e >= 0x8Du) ? 0.0f : x;
}

// probe: 1 if data at p (n logical elements) is plausibly bf16
__device__ int probe_bf16(const uint16_t* p, int n) {
    int step = n / 256; if (step < 1) step = 1;
    step |= 1;                                   // hit both parities
    for (int i = 0; i < n; i += step) {
        uint32_t e = ((uint32_t)p[i] >> 7) & 0xffu;
        if (e > 140u) return 0;                  // |x|>2^13 / inf / NaN
    }
    return 1;
}
__device__ int probe_i64(const int* p, int n) {  // odd 32b words all zero?
    int acc = 0;
    for (int i = 1; i < 2 * n && i < 128; i += 2) acc |= p[i];
    return acc == 0;
}

__global__ void detect_kernel(const void* nf, const void* ea,
                              const void* w0, const void* w1, const void* w2,
                              const int* snd, const int* rcv,
                              int snd_force64, int n_edges) {
    if (threadIdx.x == 0 && blockIdx.x == 0) {
        g_flags[0] = snd_force64 ? 1 : probe_i64(snd, n_edges > 64 ? 64 : n_edges);
        g_flags[1] = probe_i64(rcv, n_edges > 64 ? 64 : n_edges);
        g_flags[2] = probe_bf16((const uint16_t*)nf, N_NODES * FEAT);
        g_flags[3] = probe_bf16((const uint16_t*)ea, n_edges * 4);
        g_flags[4] = probe_bf16((const uint16_t*)w0, 64);
        g_flags[5] = probe_bf16((const uint16_t*)w1, 4096);
        g_flags[6] = probe_bf16((const uint16_t*)w2, 8192);
    }
}

__global__ __launch_bounds__(256) void zero_kernel() {
    int i = (blockIdx.x * 256 + threadIdx.x) * 4;
    if (i < ACC_FLOATS) *(float4*)(g_acc + i) = make_float4(0.f, 0.f, 0.f, 0.f);
}

__device__ __forceinline__ float loadf(const void* p, int i, int isbf) {
    return isbf ? b2f(((const uint16_t*)p)[i]) : ((const float*)p)[i];
}

__global__ __launch_bounds__(256) void cvt_w_kernel(
    const void* __restrict__ w0, const void* __restrict__ w1,
    const void* __restrict__ w2)
{
    int i = blockIdx.x * 256 + threadIdx.x;
    if (i < 64)             g_wf[i] = loadf(w0, i, g_flags[4]);
    else if (i < 64 + 4096) g_wf[i] = loadf(w1, i - 64, g_flags[5]);
    else if (i < NW)        g_wf[i] = loadf(w2, i - (64 + 4096), g_flags[6]);
}

// mix(ea0) LUT, one row per bf16 bit pattern. Folds /8 (layer1), /8 (layer2),
// *0.25 (1/sqrt(16)), *INV_SQRT3 on channels [32,64).
__global__ __launch_bounds__(256) void build_lut_kernel() {
    const float* w0 = g_wf;
    const float* w1 = g_wf + 64;
    const float* w2 = g_wf + 64 + 4096;
    int r = blockIdx.x * 256 + threadIdx.x;      // 0..65535 = bf16 bits
    float x = b2f((uint32_t)r);

    float h0[64];
    #pragma unroll
    for (int j = 0; j < 64; ++j) h0[j] = swishf(x * w0[j]);

    float h1[64];
    for (int j = 0; j < 64; ++j) {
        float a = 0.f;
        #pragma unroll
        for (int k = 0; k < 64; ++k) a += h0[k] * w1[k * 64 + j];
        h1[j] = swishf(a * 0.125f);
    }

    float* dst = g_lut + (size_t)r * 128;
    for (int c = 0; c < 128; c += 4) {
        float a0 = 0.f, a1 = 0.f, a2 = 0.f, a3 = 0.f;
        #pragma unroll
        for (int j = 0; j < 64; ++j) {
            float h = h1[j];
            a0 += h * w2[j * 128 + c + 0];
            a1 += h * w2[j * 128 + c + 1];
            a2 += h * w2[j * 128 + c + 2];
            a3 += h * w2[j * 128 + c + 3];
        }
        float s = 0.125f * 0.25f;
        if (c >= 32 && c < 64) s *= INV_SQRT3;
        float4 o;
        o.x = sane(a0 * s); o.y = sane(a1 * s);
        o.z = sane(a2 * s); o.w = sane(a3 * s);
        *(float4*)(dst + c) = o;
    }
}

// 32 lanes per edge, lane = channel c; 8 fp32 atomics per lane
__global__ __launch_bounds__(256) void edge_kernel(
    const void* __restrict__ nf, const void* __restrict__ ea,
    const int* __restrict__ snd, const int* __restrict__ rcv, int n_edges)
{
    int t = blockIdx.x * 256 + threadIdx.x;
    int e = t >> 5;
    int c = t & 31;
    if (e >= n_edges) return;

    uint32_t b0; float e1x, e1y, e1z;
    if (g_flags[3]) {                            // bf16 edge_attrs
        uint2 w = ((const uint2*)ea)[e];
        b0  = w.x & 0xffffu;
        e1x = b2f(w.x >> 16);
        e1y = b2f(w.y & 0xffffu);
        e1z = b2f(w.y >> 16);
    } else {                                     // fp32 edge_attrs
        float4 w = ((const float4*)ea)[e];
        b0 = f2b_bits(w.x);
        e1x = w.y; e1y = w.z; e1z = w.w;
    }
    if (b0 >= 65536u) b0 = 0;

    int si = g_flags[0] ? snd[2 * e] : snd[e];
    int ri = g_flags[1] ? rcv[2 * e] : rcv[e];
    si = min(max(si, 0), N_NODES - 1);
    ri = min(max(ri, 0), N_NODES - 1);

    const float* mix = g_lut + (size_t)b0 * 128;
    float s, v0, v1, v2;
    if (g_flags[2]) {
        const uint16_t* row = (const uint16_t*)nf + (size_t)si * FEAT;
        s  = b2f(row[c]);
        v0 = b2f(row[32 + 3 * c + 0]);
        v1 = b2f(row[32 + 3 * c + 1]);
        v2 = b2f(row[32 + 3 * c + 2]);
    } else {
        const float* row = (const float*)nf + (size_t)si * FEAT;
        s  = row[c];
        v0 = row[32 + 3 * c + 0];
        v1 = row[32 + 3 * c + 1];
        v2 = row[32 + 3 * c + 2];
    }

    float m0 = mix[c];
    float m1 = mix[32 + c];
    float m2 = mix[64 + c];
    float m3 = mix[96 + c];

    float* dst = g_acc + (size_t)ri * OUTF;
    unsafeAtomicAdd(dst + c,               s * m0);
    unsafeAtomicAdd(dst + 32 + c,          (v0 * e1x + v1 * e1y + v2 * e1z) * m1);
    unsafeAtomicAdd(dst + 64 + 3 * c + 0,  v0 * m2);
    unsafeAtomicAdd(dst + 64 + 3 * c + 1,  v1 * m2);
    unsafeAtomicAdd(dst + 64 + 3 * c + 2,  v2 * m2);
    float sm3 = s * m3;
    unsafeAtomicAdd(dst + 160 + 3 * c + 0, e1x * sm3);
    unsafeAtomicAdd(dst + 160 + 3 * c + 1, e1y * sm3);
    unsafeAtomicAdd(dst + 160 + 3 * c + 2, e1z * sm3);
}

// fp32 accumulator -> output (dtype follows node_feats' detected dtype)
__global__ __launch_bounds__(256) void cvt_out_kernel(void* __restrict__ out) {
    int i = (blockIdx.x * 256 + threadIdx.x) * 4;
    if (i >= ACC_FLOATS) return;
    float4 v = *(const float4*)(g_acc + i);
    if (g_flags[2]) {
        union { ushort4 u4; uint16_t h[4]; } o;
        o.h[0] = (uint16_t)f2b_bits(v.x);
        o.h[1] = (uint16_t)f2b_bits(v.y);
        o.h[2] = (uint16_t)f2b_bits(v.z);
        o.h[3] = (uint16_t)f2b_bits(v.w);
        *(ushort4*)((uint16_t*)out + i) = o.u4;
    } else {
        *(float4*)((float*)out + i) = v;
    }
}

extern "C" void kernel_launch(void* const* d_in, const int* in_sizes, int n_in,
                              void* d_out, int out_size, void* d_ws, size_t ws_size,
                              hipStream_t stream) {
    (void)n_in; (void)out_size; (void)d_ws; (void)ws_size;
    const void* nf = d_in[0];
    const void* ea = d_in[1];
    const int* snd = (const int*)d_in[2];
    const int* rcv = (const int*)d_in[3];
    const void* w0 = d_in[4];
    const void* w1 = d_in[5];
    const void* w2 = d_in[6];

    int n_edges = in_sizes[1] / 4;               // edge_attrs is (E,4), dtype-independent
    int snd_force64 = (in_sizes[2] == 2 * in_sizes[3]) ? 1 : 0;

    detect_kernel<<<1, 64, 0, stream>>>(nf, ea, w0, w1, w2, snd, rcv,
                                        snd_force64, n_edges);
    zero_kernel<<<(ACC_FLOATS / 4 + 255) / 256, 256, 0, stream>>>();
    cvt_w_kernel<<<(NW + 255) / 256, 256, 0, stream>>>(w0, w1, w2);
    build_lut_kernel<<<65536 / 256, 256, 0, stream>>>();
    {
        long long threads = (long long)n_edges * 32;
        int blocks = (int)((threads + 255) / 256);
        edge_kernel<<<blocks, 256, 0, stream>>>(nf, ea, snd, rcv, n_edges);
    }
    cvt_out_kernel<<<(ACC_FLOATS / 4 + 255) / 256, 256, 0, stream>>>(d_out);
}

// Round 4
// 480.240 us; speedup vs baseline: 4.6648x; 4.6648x over previous
//
#include <hip/hip_runtime.h>
#include <hip/hip_bf16.h>
#include <cstdint>

#define N_NODES   50000
#define FEAT      128
#define OUTF      256
#define MAX_EDGES 800000
#define INV_SQRT3 0.57735026918962576f
#define NW        (64 + 64*64 + 64*128)          // 12,352 weights
#define NB1       49                              // ceil(50000/1024)

// All scratch in device globals; d_ws untouched.
__device__ float g_wf[NW];
__device__ float g_lut[65536 * 128];             // 32 MB mix LUT
__device__ int   g_flags[8];                     // [0] snd i64, [1] rcv i64, [2] nf bf16, [3] ea bf16, [4..6] w bf16
__device__ int   g_cnt[N_NODES];
__device__ int   g_rowstart[N_NODES + 1];
__device__ int   g_pos[N_NODES];
__device__ int   g_bsum[64];
__device__ int   g_edge_order[MAX_EDGES];
__device__ unsigned char g_used[65536];

__device__ __forceinline__ float b2f(uint32_t b) {
    union { uint32_t u; float f; } v; v.u = b << 16; return v.f;
}
__device__ __forceinline__ uint32_t f2b_bits(float f) {
    union { float f; uint32_t u; } v; v.f = f;
    uint32_t u = v.u;
    u += 0x7fffu + ((u >> 16) & 1u);
    return u >> 16;
}
__device__ __forceinline__ float swishf(float x) {
    return x / (1.0f + __expf(-x));
}
__device__ __forceinline__ float sane(float x) {   // |x|>=2^14 / inf / NaN -> 0 (integer-domain)
    union { float f; uint32_t u; } v; v.f = x;
    return (((v.u >> 23) & 0xffu) >= 0x8Du) ? 0.0f : x;
}

// ---- dtype probes (unchanged from the passing round) ----
__device__ int probe_bf16(const uint16_t* p, int n) {
    int step = n / 256; if (step < 1) step = 1;
    step |= 1;
    for (int i = 0; i < n; i += step) {
        uint32_t e = ((uint32_t)p[i] >> 7) & 0xffu;
        if (e > 140u) return 0;
    }
    return 1;
}
__device__ int probe_i64(const int* p, int n) {
    int acc = 0;
    for (int i = 1; i < 2 * n && i < 128; i += 2) acc |= p[i];
    return acc == 0;
}
__global__ void detect_kernel(const void* nf, const void* ea,
                              const void* w0, const void* w1, const void* w2,
                              const int* snd, const int* rcv,
                              int snd_force64, int n_edges) {
    if (threadIdx.x == 0 && blockIdx.x == 0) {
        g_flags[0] = snd_force64 ? 1 : probe_i64(snd, n_edges > 64 ? 64 : n_edges);
        g_flags[1] = probe_i64(rcv, n_edges > 64 ? 64 : n_edges);
        g_flags[2] = probe_bf16((const uint16_t*)nf, N_NODES * FEAT);
        g_flags[3] = probe_bf16((const uint16_t*)ea, n_edges * 4);
        g_flags[4] = probe_bf16((const uint16_t*)w0, 64);
        g_flags[5] = probe_bf16((const uint16_t*)w1, 4096);
        g_flags[6] = probe_bf16((const uint16_t*)w2, 8192);
    }
}

__global__ __launch_bounds__(256) void zero_small_kernel() {
    int i = blockIdx.x * 256 + threadIdx.x;
    if (i < N_NODES) g_cnt[i] = 0;
    if (i < 16384)   ((int*)g_used)[i] = 0;
}

__device__ __forceinline__ float loadf(const void* p, int i, int isbf) {
    return isbf ? b2f(((const uint16_t*)p)[i]) : ((const float*)p)[i];
}
__global__ __launch_bounds__(256) void cvt_w_kernel(
    const void* __restrict__ w0, const void* __restrict__ w1, const void* __restrict__ w2) {
    int i = blockIdx.x * 256 + threadIdx.x;
    if (i < 64)             g_wf[i] = loadf(w0, i, g_flags[4]);
    else if (i < 64 + 4096) g_wf[i] = loadf(w1, i - 64, g_flags[5]);
    else if (i < NW)        g_wf[i] = loadf(w2, i - (64 + 4096), g_flags[6]);
}

// ---- CSR build: histogram (+ mark used ea0 patterns) ----
__global__ __launch_bounds__(256) void hist_kernel(
    const void* __restrict__ ea, const int* __restrict__ rcv, int n_edges) {
    int e = blockIdx.x * 256 + threadIdx.x;
    if (e >= n_edges) return;
    int ri = g_flags[1] ? rcv[2 * e] : rcv[e];
    ri = min(max(ri, 0), N_NODES - 1);
    atomicAdd(&g_cnt[ri], 1);
    uint32_t b0 = g_flags[3] ? (uint32_t)((const uint16_t*)ea)[4 * e]
                             : f2b_bits(((const float*)ea)[4 * e]);
    g_used[b0 & 0xffffu] = 1;
}

// ---- 2-level exclusive scan of g_cnt -> g_rowstart ----
__global__ __launch_bounds__(1024) void scan1_kernel() {
    __shared__ int sh[1024];
    int t = threadIdx.x, i = blockIdx.x * 1024 + t;
    int v = (i < N_NODES) ? g_cnt[i] : 0;
    sh[t] = v;
    __syncthreads();
    for (int d = 1; d < 1024; d <<= 1) {
        int x = (t >= d) ? sh[t - d] : 0;
        __syncthreads();
        sh[t] += x;
        __syncthreads();
    }
    if (i < N_NODES) g_rowstart[i] = sh[t] - v;   // exclusive
    if (t == 1023)   g_bsum[blockIdx.x] = sh[1023];
}
__global__ void scan2_kernel() {
    if (threadIdx.x == 0 && blockIdx.x == 0) {
        int acc = 0;
        for (int b = 0; b < NB1; ++b) { int x = g_bsum[b]; g_bsum[b] = acc; acc += x; }
    }
}
__global__ __launch_bounds__(1024) void scan3_kernel(int n_edges) {
    int i = blockIdx.x * 1024 + threadIdx.x;
    if (i < N_NODES) {
        int v = g_rowstart[i] + g_bsum[blockIdx.x];
        g_rowstart[i] = v;
        g_pos[i] = v;
    }
    if (i == 0) g_rowstart[N_NODES] = n_edges;
}

// ---- scatter edge ids into receiver-sorted order ----
__global__ __launch_bounds__(256) void scatter_kernel(const int* __restrict__ rcv, int n_edges) {
    int e = blockIdx.x * 256 + threadIdx.x;
    if (e >= n_edges) return;
    int ri = g_flags[1] ? rcv[2 * e] : rcv[e];
    ri = min(max(ri, 0), N_NODES - 1);
    int p = atomicAdd(&g_pos[ri], 1);
    if (p < MAX_EDGES) g_edge_order[p] = e;
}

// ---- mix(ea0) LUT; only rows whose bf16 pattern occurs. Folds /8,/8,*0.25, INV_SQRT3 ----
__global__ __launch_bounds__(256) void build_lut_kernel() {
    int r = blockIdx.x * 256 + threadIdx.x;
    if (!g_used[r]) return;
    const float* w0 = g_wf;
    const float* w1 = g_wf + 64;
    const float* w2 = g_wf + 64 + 4096;
    float x = b2f((uint32_t)r);

    float h0[64];
    #pragma unroll
    for (int j = 0; j < 64; ++j) h0[j] = swishf(x * w0[j]);

    float h1[64];
    for (int j = 0; j < 64; ++j) {
        float a = 0.f;
        #pragma unroll
        for (int k = 0; k < 64; ++k) a += h0[k] * w1[k * 64 + j];
        h1[j] = swishf(a * 0.125f);
    }

    float* dst = g_lut + (size_t)r * 128;
    for (int c = 0; c < 128; c += 4) {
        float a0 = 0.f, a1 = 0.f, a2 = 0.f, a3 = 0.f;
        #pragma unroll
        for (int j = 0; j < 64; ++j) {
            float h = h1[j];
            a0 += h * w2[j * 128 + c + 0];
            a1 += h * w2[j * 128 + c + 1];
            a2 += h * w2[j * 128 + c + 2];
            a3 += h * w2[j * 128 + c + 3];
        }
        float s = 0.125f * 0.25f;
        if (c >= 32 && c < 64) s *= INV_SQRT3;
        float4 o;
        o.x = sane(a0 * s); o.y = sane(a1 * s);
        o.z = sane(a2 * s); o.w = sane(a3 * s);
        *(float4*)(dst + c) = o;
    }
}

// ---- gather: half-wave (32 lanes = 32 channels) per node; register accumulate; no atomics ----
__global__ __launch_bounds__(256) void gather_kernel(
    const void* __restrict__ nf, const void* __restrict__ ea,
    const int* __restrict__ snd, void* __restrict__ out) {
    int t = blockIdx.x * 256 + threadIdx.x;
    int node = t >> 5;
    int c = t & 31;
    if (node >= N_NODES) return;

    const int f0 = g_flags[0], f2 = g_flags[2], f3 = g_flags[3];
    int k0 = g_rowstart[node], k1 = g_rowstart[node + 1];

    float o0 = 0.f, o1 = 0.f, o2 = 0.f, o3 = 0.f,
          o4 = 0.f, o5 = 0.f, o6 = 0.f, o7 = 0.f;

    for (int k = k0; k < k1; ++k) {
        int e = g_edge_order[k];

        uint32_t b0; float e1x, e1y, e1z;
        if (f3) {
            uint2 w = ((const uint2*)ea)[e];
            b0  = w.x & 0xffffu;
            e1x = b2f(w.x >> 16);
            e1y = b2f(w.y & 0xffffu);
            e1z = b2f(w.y >> 16);
        } else {
            float4 w = ((const float4*)ea)[e];
            b0 = f2b_bits(w.x) & 0xffffu;
            e1x = w.y; e1y = w.z; e1z = w.w;
        }
        int si = f0 ? snd[2 * e] : snd[e];
        si = min(max(si, 0), N_NODES - 1);

        const float* mix = g_lut + (size_t)b0 * 128;
        float s, v0, v1, v2;
        if (f2) {
            const uint16_t* row = (const uint16_t*)nf + (size_t)si * FEAT;
            s  = b2f(row[c]);
            v0 = b2f(row[32 + 3 * c + 0]);
            v1 = b2f(row[32 + 3 * c + 1]);
            v2 = b2f(row[32 + 3 * c + 2]);
        } else {
            const float* row = (const float*)nf + (size_t)si * FEAT;
            s  = row[c];
            v0 = row[32 + 3 * c + 0];
            v1 = row[32 + 3 * c + 1];
            v2 = row[32 + 3 * c + 2];
        }
        float m0 = mix[c], m1 = mix[32 + c], m2 = mix[64 + c], m3 = mix[96 + c];

        o0 += s * m0;
        o1 += (v0 * e1x + v1 * e1y + v2 * e1z) * m1;
        o2 += v0 * m2; o3 += v1 * m2; o4 += v2 * m2;
        float sm3 = s * m3;
        o5 += e1x * sm3; o6 += e1y * sm3; o7 += e1z * sm3;
    }

    size_t base = (size_t)node * OUTF;
    if (f2) {
        uint16_t* o = (uint16_t*)out;
        o[base + c]            = (uint16_t)f2b_bits(o0);
        o[base + 32 + c]       = (uint16_t)f2b_bits(o1);
        o[base + 64 + 3*c + 0] = (uint16_t)f2b_bits(o2);
        o[base + 64 + 3*c + 1] = (uint16_t)f2b_bits(o3);
        o[base + 64 + 3*c + 2] = (uint16_t)f2b_bits(o4);
        o[base + 160 + 3*c + 0] = (uint16_t)f2b_bits(o5);
        o[base + 160 + 3*c + 1] = (uint16_t)f2b_bits(o6);
        o[base + 160 + 3*c + 2] = (uint16_t)f2b_bits(o7);
    } else {
        float* o = (float*)out;
        o[base + c]             = o0;
        o[base + 32 + c]        = o1;
        o[base + 64 + 3*c + 0]  = o2;
        o[base + 64 + 3*c + 1]  = o3;
        o[base + 64 + 3*c + 2]  = o4;
        o[base + 160 + 3*c + 0] = o5;
        o[base + 160 + 3*c + 1] = o6;
        o[base + 160 + 3*c + 2] = o7;
    }
}

extern "C" void kernel_launch(void* const* d_in, const int* in_sizes, int n_in,
                              void* d_out, int out_size, void* d_ws, size_t ws_size,
                              hipStream_t stream) {
    (void)n_in; (void)out_size; (void)d_ws; (void)ws_size;
    const void* nf = d_in[0];
    const void* ea = d_in[1];
    const int* snd = (const int*)d_in[2];
    const int* rcv = (const int*)d_in[3];
    const void* w0 = d_in[4];
    const void* w1 = d_in[5];
    const void* w2 = d_in[6];

    int n_edges = in_sizes[1] / 4;               // edge_attrs is (E,4), dtype-independent
    if (n_edges > MAX_EDGES) n_edges = MAX_EDGES;
    int snd_force64 = (in_sizes[2] == 2 * in_sizes[3]) ? 1 : 0;
    int eb = (n_edges + 255) / 256;

    detect_kernel<<<1, 64, 0, stream>>>(nf, ea, w0, w1, w2, snd, rcv, snd_force64, n_edges);
    zero_small_kernel<<<196, 256, 0, stream>>>();
    cvt_w_kernel<<<(NW + 255) / 256, 256, 0, stream>>>(w0, w1, w2);
    hist_kernel<<<eb, 256, 0, stream>>>(ea, rcv, n_edges);
    scan1_kernel<<<NB1, 1024, 0, stream>>>();
    scan2_kernel<<<1, 64, 0, stream>>>();
    scan3_kernel<<<NB1, 1024, 0, stream>>>(n_edges);
    scatter_kernel<<<eb, 256, 0, stream>>>(rcv, n_edges);
    build_lut_kernel<<<256, 256, 0, stream>>>();
    gather_kernel<<<(N_NODES * 32 + 255) / 256, 256, 0, stream>>>(nf, ea, snd, d_out);
}

// Round 5
// 343.134 us; speedup vs baseline: 6.5288x; 1.3996x over previous
//
#include <hip/hip_runtime.h>
#include <hip/hip_bf16.h>
#include <cstdint>

#define N_NODES   50000
#define FEAT      128
#define OUTF      256
#define MAX_EDGES 800000
#define INV_SQRT3 0.57735026918962576f
#define NW        (64 + 64*64 + 64*128)          // 12,352 weights
#define NB1       49                              // ceil(50000/1024)

// All scratch in device globals; d_ws untouched.
__device__ float g_wf[NW];
__device__ float g_lut[65536 * 128];             // 32 MB mix LUT
__device__ int   g_flags[8];                     // [0] snd i64, [1] rcv i64, [2] nf bf16, [3] ea bf16, [4..6] w bf16
__device__ int   g_cnt[N_NODES];
__device__ int   g_rowstart[N_NODES + 1];
__device__ int   g_pos[N_NODES];
__device__ int   g_bsum[64];
__device__ int   g_edge_order[MAX_EDGES];
__device__ unsigned char g_used[65536];
__device__ int   g_used_list[65536];
__device__ int   g_nused;

__device__ __forceinline__ float b2f(uint32_t b) {
    union { uint32_t u; float f; } v; v.u = b << 16; return v.f;
}
__device__ __forceinline__ uint32_t f2b_bits(float f) {
    union { float f; uint32_t u; } v; v.f = f;
    uint32_t u = v.u;
    u += 0x7fffu + ((u >> 16) & 1u);
    return u >> 16;
}
__device__ __forceinline__ float swishf(float x) {
    return x / (1.0f + __expf(-x));
}
__device__ __forceinline__ float sane(float x) {   // |x|>=2^14 / inf / NaN -> 0 (integer-domain)
    union { float f; uint32_t u; } v; v.f = x;
    return (((v.u >> 23) & 0xffu) >= 0x8Du) ? 0.0f : x;
}

// ---- parallel dtype probes: one sample per thread, LDS reduce ----
__global__ __launch_bounds__(256) void detect_kernel(
    const void* nf, const void* ea,
    const void* w0, const void* w1, const void* w2,
    const int* snd, const int* rcv, int snd_force64, int n_edges)
{
    __shared__ int viol[7];
    int t = threadIdx.x;
    if (t < 7) viol[t] = 0;
    __syncthreads();

    struct P { const void* p; int n; int slot; };
    P ps[5] = { {nf, N_NODES * FEAT, 2}, {ea, n_edges * 4, 3},
                {w0, 64, 4}, {w1, 4096, 5}, {w2, 8192, 6} };
    #pragma unroll
    for (int q = 0; q < 5; ++q) {
        int n = ps[q].n;
        int step = (n / 256) | 1;                // odd -> both parities sampled
        long long i = (long long)t * step;
        if (i < n) {
            uint32_t e = (((const uint16_t*)ps[q].p)[i] >> 7) & 0xffu;
            if (e > 140u) atomicOr(&viol[ps[q].slot], 1);
        }
    }
    if (t < 64) {                                 // odd 32b words of idx arrays
        int i = 2 * t + 1;
        if (i < 2 * n_edges) {
            if (snd[i] != 0) atomicOr(&viol[0], 1);
            if (rcv[i] != 0) atomicOr(&viol[1], 1);
        }
    }
    __syncthreads();
    if (t == 0) {
        g_flags[0] = snd_force64 ? 1 : !viol[0];
        g_flags[1] = !viol[1];
        g_flags[2] = !viol[2];
        g_flags[3] = !viol[3];
        g_flags[4] = !viol[4];
        g_flags[5] = !viol[5];
        g_flags[6] = !viol[6];
    }
}

__global__ __launch_bounds__(256) void zero_small_kernel() {
    int i = blockIdx.x * 256 + threadIdx.x;
    if (i < N_NODES) g_cnt[i] = 0;
    if (i < 16384)   ((int*)g_used)[i] = 0;
    if (i == 0)      g_nused = 0;
}

__device__ __forceinline__ float loadf(const void* p, int i, int isbf) {
    return isbf ? b2f(((const uint16_t*)p)[i]) : ((const float*)p)[i];
}
__global__ __launch_bounds__(256) void cvt_w_kernel(
    const void* __restrict__ w0, const void* __restrict__ w1, const void* __restrict__ w2) {
    int i = blockIdx.x * 256 + threadIdx.x;
    if (i < 64)             g_wf[i] = loadf(w0, i, g_flags[4]);
    else if (i < 64 + 4096) g_wf[i] = loadf(w1, i - 64, g_flags[5]);
    else if (i < NW)        g_wf[i] = loadf(w2, i - (64 + 4096), g_flags[6]);
}

// ---- CSR build: histogram (+ mark used ea0 patterns) ----
__global__ __launch_bounds__(256) void hist_kernel(
    const void* __restrict__ ea, const int* __restrict__ rcv, int n_edges) {
    int e = blockIdx.x * 256 + threadIdx.x;
    if (e >= n_edges) return;
    int ri = g_flags[1] ? rcv[2 * e] : rcv[e];
    ri = min(max(ri, 0), N_NODES - 1);
    atomicAdd(&g_cnt[ri], 1);
    uint32_t b0 = g_flags[3] ? (uint32_t)((const uint16_t*)ea)[4 * e]
                             : f2b_bits(((const float*)ea)[4 * e]);
    g_used[b0 & 0xffffu] = 1;
}

// ---- 2-level exclusive scan of g_cnt -> g_rowstart ----
__global__ __launch_bounds__(1024) void scan1_kernel() {
    __shared__ int sh[1024];
    int t = threadIdx.x, i = blockIdx.x * 1024 + t;
    int v = (i < N_NODES) ? g_cnt[i] : 0;
    sh[t] = v;
    __syncthreads();
    for (int d = 1; d < 1024; d <<= 1) {
        int x = (t >= d) ? sh[t - d] : 0;
        __syncthreads();
        sh[t] += x;
        __syncthreads();
    }
    if (i < N_NODES) g_rowstart[i] = sh[t] - v;   // exclusive
    if (t == 1023)   g_bsum[blockIdx.x] = sh[1023];
}
__global__ void scan2_kernel() {
    if (threadIdx.x == 0 && blockIdx.x == 0) {
        int acc = 0;
        for (int b = 0; b < NB1; ++b) { int x = g_bsum[b]; g_bsum[b] = acc; acc += x; }
    }
}
__global__ __launch_bounds__(1024) void scan3_kernel(int n_edges) {
    int i = blockIdx.x * 1024 + threadIdx.x;
    if (i < N_NODES) {
        int v = g_rowstart[i] + g_bsum[blockIdx.x];
        g_rowstart[i] = v;
        g_pos[i] = v;
    }
    if (i == 0) g_rowstart[N_NODES] = n_edges;
}

// ---- scatter edge ids into receiver-sorted order ----
__global__ __launch_bounds__(256) void scatter_kernel(const int* __restrict__ rcv, int n_edges) {
    int e = blockIdx.x * 256 + threadIdx.x;
    if (e >= n_edges) return;
    int ri = g_flags[1] ? rcv[2 * e] : rcv[e];
    ri = min(max(ri, 0), N_NODES - 1);
    int p = atomicAdd(&g_pos[ri], 1);
    if (p < MAX_EDGES) g_edge_order[p] = e;
}

// ---- compact used ea0 patterns into a dense list ----
__global__ __launch_bounds__(256) void compact_kernel() {
    int r = blockIdx.x * 256 + threadIdx.x;
    if (r < 65536 && g_used[r]) {
        int p = atomicAdd(&g_nused, 1);
        g_used_list[p] = r;
    }
}

// ---- wave-parallel LUT build: one 64-lane wave per used row ----
// lane = hidden unit j; layer sums via __shfl broadcast; 2 out channels/lane.
// Folds /8 (layer1... none), /8 (layer2), /8*0.25 (layer3+1/sqrt16), INV_SQRT3 on ch [32,64).
__global__ __launch_bounds__(256) void build_lut_kernel() {
    int nwaves = gridDim.x * 4;                  // 4 waves per 256-block
    int wave0 = (blockIdx.x * 256 + threadIdx.x) >> 6;
    int lane = threadIdx.x & 63;
    int nused = g_nused;
    const float* w1 = g_wf + 64;
    const float* w2 = g_wf + 64 + 4096;
    float w0l = g_wf[lane];

    for (int w = wave0; w < nused; w += nwaves) {
        int r = g_used_list[w];
        float x = b2f((uint32_t)r);
        float h0 = swishf(x * w0l);

        float a = 0.f;
        #pragma unroll 8
        for (int k = 0; k < 64; ++k) {
            float h0k = __shfl(h0, k, 64);
            a += h0k * w1[k * 64 + lane];
        }
        float h1 = swishf(a * 0.125f);

        float a0 = 0.f, a1 = 0.f;
        #pragma unroll 8
        for (int k = 0; k < 64; ++k) {
            float h1k = __shfl(h1, k, 64);
            a0 += h1k * w2[k * 128 + lane];
            a1 += h1k * w2[k * 128 + 64 + lane];
        }
        float s0 = 0.125f * 0.25f, s1 = 0.125f * 0.25f;
        if (lane >= 32) s0 *= INV_SQRT3;         // channels [32,64)
        float* dst = g_lut + (size_t)r * 128;
        dst[lane]      = sane(a0 * s0);
        dst[64 + lane] = sane(a1 * s1);
    }
}

// ---- gather: half-wave (32 lanes = 32 channels) per node; register accumulate; no atomics ----
__global__ __launch_bounds__(256) void gather_kernel(
    const void* __restrict__ nf, const void* __restrict__ ea,
    const int* __restrict__ snd, void* __restrict__ out) {
    int t = blockIdx.x * 256 + threadIdx.x;
    int node = t >> 5;
    int c = t & 31;
    if (node >= N_NODES) return;

    const int f0 = g_flags[0], f2 = g_flags[2], f3 = g_flags[3];
    int k0 = g_rowstart[node], k1 = g_rowstart[node + 1];

    float o0 = 0.f, o1 = 0.f, o2 = 0.f, o3 = 0.f,
          o4 = 0.f, o5 = 0.f, o6 = 0.f, o7 = 0.f;

    for (int k = k0; k < k1; ++k) {
        int e = g_edge_order[k];

        uint32_t b0; float e1x, e1y, e1z;
        if (f3) {
            uint2 w = ((const uint2*)ea)[e];
            b0  = w.x & 0xffffu;
            e1x = b2f(w.x >> 16);
            e1y = b2f(w.y & 0xffffu);
            e1z = b2f(w.y >> 16);
        } else {
            float4 w = ((const float4*)ea)[e];
            b0 = f2b_bits(w.x) & 0xffffu;
            e1x = w.y; e1y = w.z; e1z = w.w;
        }
        int si = f0 ? snd[2 * e] : snd[e];
        si = min(max(si, 0), N_NODES - 1);

        const float* mix = g_lut + (size_t)b0 * 128;
        float s, v0, v1, v2;
        if (f2) {
            const uint16_t* row = (const uint16_t*)nf + (size_t)si * FEAT;
            s  = b2f(row[c]);
            v0 = b2f(row[32 + 3 * c + 0]);
            v1 = b2f(row[32 + 3 * c + 1]);
            v2 = b2f(row[32 + 3 * c + 2]);
        } else {
            const float* row = (const float*)nf + (size_t)si * FEAT;
            s  = row[c];
            v0 = row[32 + 3 * c + 0];
            v1 = row[32 + 3 * c + 1];
            v2 = row[32 + 3 * c + 2];
        }
        float m0 = mix[c], m1 = mix[32 + c], m2 = mix[64 + c], m3 = mix[96 + c];

        o0 += s * m0;
        o1 += (v0 * e1x + v1 * e1y + v2 * e1z) * m1;
        o2 += v0 * m2; o3 += v1 * m2; o4 += v2 * m2;
        float sm3 = s * m3;
        o5 += e1x * sm3; o6 += e1y * sm3; o7 += e1z * sm3;
    }

    size_t base = (size_t)node * OUTF;
    if (f2) {
        uint16_t* o = (uint16_t*)out;
        o[base + c]             = (uint16_t)f2b_bits(o0);
        o[base + 32 + c]        = (uint16_t)f2b_bits(o1);
        o[base + 64 + 3*c + 0]  = (uint16_t)f2b_bits(o2);
        o[base + 64 + 3*c + 1]  = (uint16_t)f2b_bits(o3);
        o[base + 64 + 3*c + 2]  = (uint16_t)f2b_bits(o4);
        o[base + 160 + 3*c + 0] = (uint16_t)f2b_bits(o5);
        o[base + 160 + 3*c + 1] = (uint16_t)f2b_bits(o6);
        o[base + 160 + 3*c + 2] = (uint16_t)f2b_bits(o7);
    } else {
        float* o = (float*)out;
        o[base + c]             = o0;
        o[base + 32 + c]        = o1;
        o[base + 64 + 3*c + 0]  = o2;
        o[base + 64 + 3*c + 1]  = o3;
        o[base + 64 + 3*c + 2]  = o4;
        o[base + 160 + 3*c + 0] = o5;
        o[base + 160 + 3*c + 1] = o6;
        o[base + 160 + 3*c + 2] = o7;
    }
}

extern "C" void kernel_launch(void* const* d_in, const int* in_sizes, int n_in,
                              void* d_out, int out_size, void* d_ws, size_t ws_size,
                              hipStream_t stream) {
    (void)n_in; (void)out_size; (void)d_ws; (void)ws_size;
    const void* nf = d_in[0];
    const void* ea = d_in[1];
    const int* snd = (const int*)d_in[2];
    const int* rcv = (const int*)d_in[3];
    const void* w0 = d_in[4];
    const void* w1 = d_in[5];
    const void* w2 = d_in[6];

    int n_edges = in_sizes[1] / 4;               // edge_attrs is (E,4), dtype-independent
    if (n_edges > MAX_EDGES) n_edges = MAX_EDGES;
    int snd_force64 = (in_sizes[2] == 2 * in_sizes[3]) ? 1 : 0;
    int eb = (n_edges + 255) / 256;

    detect_kernel<<<1, 256, 0, stream>>>(nf, ea, w0, w1, w2, snd, rcv, snd_force64, n_edges);
    zero_small_kernel<<<196, 256, 0, stream>>>();
    cvt_w_kernel<<<(NW + 255) / 256, 256, 0, stream>>>(w0, w1, w2);
    hist_kernel<<<eb, 256, 0, stream>>>(ea, rcv, n_edges);
    scan1_kernel<<<NB1, 1024, 0, stream>>>();
    scan2_kernel<<<1, 64, 0, stream>>>();
    scan3_kernel<<<NB1, 1024, 0, stream>>>(n_edges);
    scatter_kernel<<<eb, 256, 0, stream>>>(rcv, n_edges);
    compact_kernel<<<256, 256, 0, stream>>>();
    build_lut_kernel<<<1024, 256, 0, stream>>>();
    gather_kernel<<<(N_NODES * 32 + 255) / 256, 256, 0, stream>>>(nf, ea, snd, d_out);
}

// Round 6
// 296.357 us; speedup vs baseline: 7.5593x; 1.1578x over previous
//
#include <hip/hip_runtime.h>
#include <hip/hip_bf16.h>
#include <cstdint>

#define N_NODES   50000
#define FEAT      128
#define OUTF      256
#define MAX_EDGES 800000
#define INV_SQRT3 0.57735026918962576f
#define NW        (64 + 64*64 + 64*128)          // 12,352 weights
#define NB1       49                              // ceil(50000/1024)

// All scratch in device globals; d_ws untouched.
__device__ float g_wf[NW];
__device__ float g_lut[65536 * 128];             // 32 MB mix LUT
__device__ int   g_flags[8];                     // [0] snd i64, [1] rcv i64, [2] nf bf16, [3] ea bf16, [4..6] w bf16
__device__ int   g_cnt[N_NODES];
__device__ int   g_rowstart[N_NODES + 1];
__device__ int   g_pos[N_NODES];
__device__ int   g_bsum[64];
__device__ int   g_edge_order[MAX_EDGES];
__device__ unsigned char g_used[65536];
__device__ int   g_used_list[65536];
__device__ int   g_nused;

__device__ __forceinline__ float b2f(uint32_t b) {
    union { uint32_t u; float f; } v; v.u = b << 16; return v.f;
}
__device__ __forceinline__ uint32_t f2b_bits(float f) {
    union { float f; uint32_t u; } v; v.f = f;
    uint32_t u = v.u;
    u += 0x7fffu + ((u >> 16) & 1u);
    return u >> 16;
}
__device__ __forceinline__ float swishf(float x) {
    return x / (1.0f + __expf(-x));
}
__device__ __forceinline__ float sane(float x) {   // |x|>=2^14 / inf / NaN -> 0 (integer-domain)
    union { float f; uint32_t u; } v; v.f = x;
    return (((v.u >> 23) & 0xffu) >= 0x8Du) ? 0.0f : x;
}
__device__ __forceinline__ float loadf(const void* p, int i, int isbf) {
    return isbf ? b2f(((const uint16_t*)p)[i]) : ((const float*)p)[i];
}

// ---- fused: block 0 = dtype probes; blocks 1..196 = zero counters/flags ----
__global__ __launch_bounds__(256) void init_kernel(
    const void* nf, const void* ea, const void* w0, const void* w1, const void* w2,
    const int* snd, const int* rcv, int snd_force64, int n_edges)
{
    if (blockIdx.x == 0) {
        __shared__ int viol[7];
        int t = threadIdx.x;
        if (t < 7) viol[t] = 0;
        __syncthreads();
        const void* ptrs[5] = { nf, ea, w0, w1, w2 };
        const int ns[5] = { N_NODES * FEAT, n_edges * 4, 64, 4096, 8192 };
        #pragma unroll
        for (int q = 0; q < 5; ++q) {
            int n = ns[q];
            int step = (n / 256) | 1;            // odd -> both parities sampled
            long long i = (long long)t * step;
            if (i < n) {
                uint32_t e = (((const uint16_t*)ptrs[q])[i] >> 7) & 0xffu;
                if (e > 140u) atomicOr(&viol[q + 2], 1);
            }
        }
        if (t < 64) {                            // odd 32b words of idx arrays
            int i = 2 * t + 1;
            if (i < 2 * n_edges) {
                if (snd[i] != 0) atomicOr(&viol[0], 1);
                if (rcv[i] != 0) atomicOr(&viol[1], 1);
            }
        }
        __syncthreads();
        if (t == 0) {
            g_flags[0] = snd_force64 ? 1 : !viol[0];
            g_flags[1] = !viol[1];
            g_flags[2] = !viol[2];
            g_flags[3] = !viol[3];
            g_flags[4] = !viol[4];
            g_flags[5] = !viol[5];
            g_flags[6] = !viol[6];
        }
    } else {
        int i = (blockIdx.x - 1) * 256 + threadIdx.x;
        if (i < N_NODES) g_cnt[i] = 0;
        if (i < 16384)   ((int*)g_used)[i] = 0;
        if (i == 0)      g_nused = 0;
    }
}

// ---- fused: blocks [0,eb) = histogram + used-pattern marking; rest = weight cvt ----
__global__ __launch_bounds__(256) void histw_kernel(
    const void* __restrict__ ea, const int* __restrict__ rcv,
    const void* __restrict__ w0, const void* __restrict__ w1,
    const void* __restrict__ w2, int n_edges, int eb)
{
    if ((int)blockIdx.x < eb) {
        int e = blockIdx.x * 256 + threadIdx.x;
        if (e >= n_edges) return;
        int ri = g_flags[1] ? rcv[2 * e] : rcv[e];
        ri = min(max(ri, 0), N_NODES - 1);
        atomicAdd(&g_cnt[ri], 1);
        uint32_t b0 = g_flags[3] ? (uint32_t)((const uint16_t*)ea)[4 * e]
                                 : f2b_bits(((const float*)ea)[4 * e]);
        g_used[b0 & 0xffffu] = 1;
    } else {
        int i = (blockIdx.x - eb) * 256 + threadIdx.x;
        if (i < 64)             g_wf[i] = loadf(w0, i, g_flags[4]);
        else if (i < 64 + 4096) g_wf[i] = loadf(w1, i - 64, g_flags[5]);
        else if (i < NW)        g_wf[i] = loadf(w2, i - (64 + 4096), g_flags[6]);
    }
}

// ---- scan level 1: per-1024-block inclusive scan ----
__global__ __launch_bounds__(1024) void scan1_kernel() {
    __shared__ int sh[1024];
    int t = threadIdx.x, i = blockIdx.x * 1024 + t;
    int v = (i < N_NODES) ? g_cnt[i] : 0;
    sh[t] = v;
    __syncthreads();
    for (int d = 1; d < 1024; d <<= 1) {
        int x = (t >= d) ? sh[t - d] : 0;
        __syncthreads();
        sh[t] += x;
        __syncthreads();
    }
    if (i < N_NODES) g_rowstart[i] = sh[t] - v;   // exclusive
    if (t == 1023)   g_bsum[blockIdx.x] = sh[1023];
}
// ---- scan level 2: single-wave shfl prefix over 49 block sums ----
__global__ void scan2_kernel() {
    int t = threadIdx.x;                          // blockDim = 64
    int v = (t < NB1) ? g_bsum[t] : 0;
    int orig = v;
    for (int d = 1; d < 64; d <<= 1) {
        int x = __shfl_up(v, d, 64);
        if (t >= d) v += x;
    }
    if (t < NB1) g_bsum[t] = v - orig;            // exclusive
}
// ---- fused: blocks [0,49) add block offsets; blocks [49,113) compact used list ----
__global__ __launch_bounds__(1024) void scan3c_kernel(int n_edges) {
    if ((int)blockIdx.x < NB1) {
        int i = blockIdx.x * 1024 + threadIdx.x;
        if (i < N_NODES) {
            int v = g_rowstart[i] + g_bsum[blockIdx.x];
            g_rowstart[i] = v;
            g_pos[i] = v;
        }
        if (i == 0) g_rowstart[N_NODES] = n_edges;
    } else {
        int r = (blockIdx.x - NB1) * 1024 + threadIdx.x;
        if (r < 65536 && g_used[r]) {
            int p = atomicAdd(&g_nused, 1);
            g_used_list[p] = r;
        }
    }
}

// ---- fused: blocks [0,eb) scatter edge ids; blocks [eb,eb+1024) wave-parallel LUT ----
__global__ __launch_bounds__(256) void scatlut_kernel(
    const int* __restrict__ rcv, int n_edges, int eb)
{
    if ((int)blockIdx.x < eb) {
        int e = blockIdx.x * 256 + threadIdx.x;
        if (e >= n_edges) return;
        int ri = g_flags[1] ? rcv[2 * e] : rcv[e];
        ri = min(max(ri, 0), N_NODES - 1);
        int p = atomicAdd(&g_pos[ri], 1);
        if (p < MAX_EDGES) g_edge_order[p] = e;
    } else {
        int lb = blockIdx.x - eb;                 // 0..1023
        int nwaves = 1024 * 4;
        int wave0 = lb * 4 + (threadIdx.x >> 6);
        int lane = threadIdx.x & 63;
        int nused = g_nused;
        const float* w1 = g_wf + 64;
        const float* w2 = g_wf + 64 + 4096;
        float w0l = g_wf[lane];
        for (int w = wave0; w < nused; w += nwaves) {
            int r = g_used_list[w];
            float x = b2f((uint32_t)r);
            float h0 = swishf(x * w0l);
            float a = 0.f;
            #pragma unroll 8
            for (int k = 0; k < 64; ++k)
                a += __shfl(h0, k, 64) * w1[k * 64 + lane];
            float h1 = swishf(a * 0.125f);
            float a0 = 0.f, a1 = 0.f;
            #pragma unroll 8
            for (int k = 0; k < 64; ++k) {
                float h1k = __shfl(h1, k, 64);
                a0 += h1k * w2[k * 128 + lane];
                a1 += h1k * w2[k * 128 + 64 + lane];
            }
            float s0 = 0.125f * 0.25f, s1 = 0.125f * 0.25f;
            if (lane >= 32) s0 *= INV_SQRT3;      // channels [32,64)
            float* dst = g_lut + (size_t)r * 128;
            dst[lane]      = sane(a0 * s0);
            dst[64 + lane] = sane(a1 * s1);
        }
    }
}

// ---- gather v2: one wave per node; preload indices in parallel; 2 edges/iter ----
__global__ __launch_bounds__(256) void gather_kernel(
    const void* __restrict__ nf, const void* __restrict__ ea,
    const int* __restrict__ snd, void* __restrict__ out)
{
    int wid = (blockIdx.x * 256 + threadIdx.x) >> 6;
    int lane = threadIdx.x & 63;
    if (wid >= N_NODES) return;
    int c = lane & 31;
    int half = lane >> 5;
    const int f0 = g_flags[0], f2 = g_flags[2], f3 = g_flags[3];
    int k0 = g_rowstart[wid], k1 = g_rowstart[wid + 1];
    int deg = k1 - k0;

    float o0 = 0.f, o1 = 0.f, o2 = 0.f, o3 = 0.f,
          o4 = 0.f, o5 = 0.f, o6 = 0.f, o7 = 0.f;

    for (int base = 0; base < deg; base += 64) {
        int nchunk = min(64, deg - base);
        // preload: lane j holds edge j's indices/attrs — all loads in flight at once
        int si_p = 0, b0_p = 0;
        float ex_p = 0.f, ey_p = 0.f, ez_p = 0.f;
        if (lane < nchunk) {
            int e = g_edge_order[k0 + base + lane];
            if (f3) {
                uint2 w = ((const uint2*)ea)[e];
                b0_p = (int)(w.x & 0xffffu);
                ex_p = b2f(w.x >> 16);
                ey_p = b2f(w.y & 0xffffu);
                ez_p = b2f(w.y >> 16);
            } else {
                float4 w = ((const float4*)ea)[e];
                b0_p = (int)(f2b_bits(w.x) & 0xffffu);
                ex_p = w.y; ey_p = w.z; ez_p = w.w;
            }
            int s_ = f0 ? snd[2 * e] : snd[e];
            si_p = min(max(s_, 0), N_NODES - 1);
        }
        // 2 edges per iteration: lanes 0-31 edge j, lanes 32-63 edge j+1
        for (int j = 0; j < nchunk; j += 2) {
            int jj = j + half;
            float gate = (jj < nchunk) ? 1.0f : 0.0f;
            int jx = (jj < nchunk) ? jj : 0;
            int   si  = __shfl(si_p, jx, 64);
            int   b0  = __shfl(b0_p, jx, 64);
            float e1x = __shfl(ex_p, jx, 64);
            float e1y = __shfl(ey_p, jx, 64);
            float e1z = __shfl(ez_p, jx, 64);

            const float* mix = g_lut + (size_t)b0 * 128;
            float m0 = mix[c] * gate, m1 = mix[32 + c] * gate,
                  m2 = mix[64 + c] * gate, m3 = mix[96 + c] * gate;

            float s, v0, v1, v2;
            if (f2) {
                const uint16_t* row = (const uint16_t*)nf + (size_t)si * FEAT;
                s  = b2f(row[c]);
                v0 = b2f(row[32 + 3 * c + 0]);
                v1 = b2f(row[32 + 3 * c + 1]);
                v2 = b2f(row[32 + 3 * c + 2]);
            } else {
                const float* row = (const float*)nf + (size_t)si * FEAT;
                s  = row[c];
                v0 = row[32 + 3 * c + 0];
                v1 = row[32 + 3 * c + 1];
                v2 = row[32 + 3 * c + 2];
            }
            o0 += s * m0;
            o1 += (v0 * e1x + v1 * e1y + v2 * e1z) * m1;
            o2 += v0 * m2; o3 += v1 * m2; o4 += v2 * m2;
            float sm3 = s * m3;
            o5 += e1x * sm3; o6 += e1y * sm3; o7 += e1z * sm3;
        }
    }

    // merge the two half-wave partial sums
    o0 += __shfl_xor(o0, 32, 64);
    o1 += __shfl_xor(o1, 32, 64);
    o2 += __shfl_xor(o2, 32, 64);
    o3 += __shfl_xor(o3, 32, 64);
    o4 += __shfl_xor(o4, 32, 64);
    o5 += __shfl_xor(o5, 32, 64);
    o6 += __shfl_xor(o6, 32, 64);
    o7 += __shfl_xor(o7, 32, 64);

    if (half == 0) {
        size_t bo = (size_t)wid * OUTF;
        if (f2) {
            uint16_t* o = (uint16_t*)out;
            o[bo + c]             = (uint16_t)f2b_bits(o0);
            o[bo + 32 + c]        = (uint16_t)f2b_bits(o1);
            o[bo + 64 + 3*c + 0]  = (uint16_t)f2b_bits(o2);
            o[bo + 64 + 3*c + 1]  = (uint16_t)f2b_bits(o3);
            o[bo + 64 + 3*c + 2]  = (uint16_t)f2b_bits(o4);
            o[bo + 160 + 3*c + 0] = (uint16_t)f2b_bits(o5);
            o[bo + 160 + 3*c + 1] = (uint16_t)f2b_bits(o6);
            o[bo + 160 + 3*c + 2] = (uint16_t)f2b_bits(o7);
        } else {
            float* o = (float*)out;
            o[bo + c]             = o0;
            o[bo + 32 + c]        = o1;
            o[bo + 64 + 3*c + 0]  = o2;
            o[bo + 64 + 3*c + 1]  = o3;
            o[bo + 64 + 3*c + 2]  = o4;
            o[bo + 160 + 3*c + 0] = o5;
            o[bo + 160 + 3*c + 1] = o6;
            o[bo + 160 + 3*c + 2] = o7;
        }
    }
}

extern "C" void kernel_launch(void* const* d_in, const int* in_sizes, int n_in,
                              void* d_out, int out_size, void* d_ws, size_t ws_size,
                              hipStream_t stream) {
    (void)n_in; (void)out_size; (void)d_ws; (void)ws_size;
    const void* nf = d_in[0];
    const void* ea = d_in[1];
    const int* snd = (const int*)d_in[2];
    const int* rcv = (const int*)d_in[3];
    const void* w0 = d_in[4];
    const void* w1 = d_in[5];
    const void* w2 = d_in[6];

    int n_edges = in_sizes[1] / 4;               // edge_attrs is (E,4), dtype-independent
    if (n_edges > MAX_EDGES) n_edges = MAX_EDGES;
    int snd_force64 = (in_sizes[2] == 2 * in_sizes[3]) ? 1 : 0;
    int eb = (n_edges + 255) / 256;

    init_kernel<<<197, 256, 0, stream>>>(nf, ea, w0, w1, w2, snd, rcv, snd_force64, n_edges);
    histw_kernel<<<eb + 49, 256, 0, stream>>>(ea, rcv, w0, w1, w2, n_edges, eb);
    scan1_kernel<<<NB1, 1024, 0, stream>>>();
    scan2_kernel<<<1, 64, 0, stream>>>();
    scan3c_kernel<<<NB1 + 64, 1024, 0, stream>>>(n_edges);
    scatlut_kernel<<<eb + 1024, 256, 0, stream>>>(rcv, n_edges, eb);
    gather_kernel<<<(N_NODES + 3) / 4, 256, 0, stream>>>(nf, ea, snd, d_out);
}